// Round 7
// baseline (399.875 us; speedup 1.0000x reference)
//
#include <hip/hip_runtime.h>
#include <hip/hip_bf16.h>

#define N_ROWS 131072
#define D_IN   512
#define DK     64

typedef short bf16x8 __attribute__((ext_vector_type(8)));
typedef float f32x4  __attribute__((ext_vector_type(4)));

__device__ __forceinline__ unsigned short f2bf(float f) {
    union { float f; unsigned u; } v; v.f = f;
    unsigned r = v.u + 0x7FFFu + ((v.u >> 16) & 1u);   // RNE
    return (unsigned short)(r >> 16);
}
__device__ __forceinline__ float bf2f(unsigned short h) {
    union { unsigned u; float f; } v; v.u = ((unsigned)h) << 16;
    return v.f;
}
__device__ __forceinline__ float phi_f(float x) {
    return x > 0.f ? (x + 1.f) : __expf(x);   // elu(x)+1
}

// ---------------------------------------------------------------- prep ----
// Pack [Wq|Wk|Wv] -> transposed bf16 W_bfT[192][512]. (finals zeroing dropped:
// la_reduce v2 overwrites finals directly, no atomics.)
__global__ void la_prep(const float* __restrict__ Wq, const float* __restrict__ Wk,
                        const float* __restrict__ Wv, unsigned short* __restrict__ wbfT) {
    int idx = blockIdx.x * 1024 + threadIdx.x;
    if (idx < 192 * 512) {
        int cc = idx >> 9;            // 0..191 output feature
        int k  = idx & 511;           // 0..511 input feature
        const float* W = (cc < 64) ? Wq : (cc < 128 ? Wk : Wv);
        wbfT[idx] = f2bf(W[k * DK + (cc & 63)]);
    }
}

// ---------------------------------------------------------------- main ----
// BM=128, BK=64, 12 waves = 4 row-groups x 3 sections (Q,K,V).
// v2 pipeline (unchanged this round): double-buffered LDS, reg-staged
// prefetch, ONE barrier per K-iteration.
#define XS 72    // X LDS row stride (bf16): 144 B = 9*16 -> 2-way max
#define WSR 72   // W LDS row stride
#define TS 136   // transposed KphiT/VT row stride: 272 B = 17*16

__global__ __launch_bounds__(768) void la_main(
    const float* __restrict__ X, const unsigned short* __restrict__ wbfT,
    unsigned short* __restrict__ qphi, float* __restrict__ part)
{
    __shared__ __align__(16) char smem[92160];
    __shared__ float ksum_lds[64];

    unsigned short* xsb[2] = { (unsigned short*)smem,
                               (unsigned short*)(smem + 18432) };
    unsigned short* wsb[2] = { (unsigned short*)(smem + 36864),
                               (unsigned short*)(smem + 64512) };
    unsigned short* kT = (unsigned short*)smem;             // [64][136] overlay
    unsigned short* vT = (unsigned short*)(smem + 17408);   // [64][136] overlay

    const int tid = threadIdx.x;
    const int w   = tid >> 6;
    const int l   = tid & 63;
    const int c   = l & 15;
    const int g   = l >> 4;
    const int sec = w % 3;         // 0=Q 1=K 2=V
    const int r   = w / 3;         // row group 0..3
    const long rowBase = (long)blockIdx.x * 128;

    if (tid < 64) ksum_lds[tid] = 0.f;

    f32x4 acc[2][4];
#pragma unroll
    for (int m = 0; m < 2; ++m)
#pragma unroll
        for (int f = 0; f < 4; ++f) acc[m][f] = (f32x4){0.f, 0.f, 0.f, 0.f};

    // staging registers (single live copy; rewritten each iter)
    float4 xr0, xr1, xr2, xr3;     // threads 0..511: X slots tid+512j
    float4 wr0, wr1;               // all threads:   W slots tid+768j

    const int xsl = tid;           // X slot base (valid when tid<512)
    const int xrl0 = (xsl) >> 4,          xc0 = (xsl) & 15;
    const int xrl1 = (xsl + 512) >> 4,    xc1 = (xsl + 512) & 15;
    const int xrl2 = (xsl + 1024) >> 4,   xc2 = (xsl + 1024) & 15;
    const int xrl3 = (xsl + 1536) >> 4,   xc3 = (xsl + 1536) & 15;
    const int wcc0 = tid >> 3,           wch0 = tid & 7;
    const int wcc1 = (tid + 768) >> 3,   wch1 = (tid + 768) & 7;

    // prologue: issue loads for kb=0
    {
        const int k0 = 0;
        if (tid < 512) {
            xr0 = *(const float4*)(X + (rowBase + xrl0) * D_IN + k0 + (xc0 << 2));
            xr1 = *(const float4*)(X + (rowBase + xrl1) * D_IN + k0 + (xc1 << 2));
            xr2 = *(const float4*)(X + (rowBase + xrl2) * D_IN + k0 + (xc2 << 2));
            xr3 = *(const float4*)(X + (rowBase + xrl3) * D_IN + k0 + (xc3 << 2));
        }
        wr0 = *(const float4*)(wbfT + wcc0 * D_IN + k0 + (wch0 << 3));
        wr1 = *(const float4*)(wbfT + wcc1 * D_IN + k0 + (wch1 << 3));
    }

#pragma unroll
    for (int kb = 0; kb < 8; ++kb) {
        unsigned short* xs  = xsb[kb & 1];
        unsigned short* wsm = wsb[kb & 1];
        // --- step 1: write tile kb from regs into buf[kb&1]
        if (tid < 512) {
            {   const unsigned u0 = (unsigned)f2bf(xr0.x) | ((unsigned)f2bf(xr0.y) << 16);
                const unsigned u1 = (unsigned)f2bf(xr0.z) | ((unsigned)f2bf(xr0.w) << 16);
                *(uint2*)(xs + xrl0 * XS + (xc0 << 2)) = make_uint2(u0, u1); }
            {   const unsigned u0 = (unsigned)f2bf(xr1.x) | ((unsigned)f2bf(xr1.y) << 16);
                const unsigned u1 = (unsigned)f2bf(xr1.z) | ((unsigned)f2bf(xr1.w) << 16);
                *(uint2*)(xs + xrl1 * XS + (xc1 << 2)) = make_uint2(u0, u1); }
            {   const unsigned u0 = (unsigned)f2bf(xr2.x) | ((unsigned)f2bf(xr2.y) << 16);
                const unsigned u1 = (unsigned)f2bf(xr2.z) | ((unsigned)f2bf(xr2.w) << 16);
                *(uint2*)(xs + xrl2 * XS + (xc2 << 2)) = make_uint2(u0, u1); }
            {   const unsigned u0 = (unsigned)f2bf(xr3.x) | ((unsigned)f2bf(xr3.y) << 16);
                const unsigned u1 = (unsigned)f2bf(xr3.z) | ((unsigned)f2bf(xr3.w) << 16);
                *(uint2*)(xs + xrl3 * XS + (xc3 << 2)) = make_uint2(u0, u1); }
        }
        *(float4*)(wsm + wcc0 * WSR + (wch0 << 3)) = wr0;
        *(float4*)(wsm + wcc1 * WSR + (wch1 << 3)) = wr1;
        // --- step 2
        __syncthreads();
        // --- step 3: prefetch tile kb+1
        if (kb < 7) {
            const int k0 = (kb + 1) * 64;
            if (tid < 512) {
                xr0 = *(const float4*)(X + (rowBase + xrl0) * D_IN + k0 + (xc0 << 2));
                xr1 = *(const float4*)(X + (rowBase + xrl1) * D_IN + k0 + (xc1 << 2));
                xr2 = *(const float4*)(X + (rowBase + xrl2) * D_IN + k0 + (xc2 << 2));
                xr3 = *(const float4*)(X + (rowBase + xrl3) * D_IN + k0 + (xc3 << 2));
            }
            wr0 = *(const float4*)(wbfT + wcc0 * D_IN + k0 + (wch0 << 3));
            wr1 = *(const float4*)(wbfT + wcc1 * D_IN + k0 + (wch1 << 3));
        }
        // --- step 4: compute on buf[kb&1]
#pragma unroll
        for (int ks = 0; ks < 2; ++ks) {
            const int ko = ks * 32 + g * 8;
            bf16x8 a[2], b[4];
#pragma unroll
            for (int m = 0; m < 2; ++m)
                a[m] = *(const bf16x8*)(xs + (r * 32 + m * 16 + c) * XS + ko);
#pragma unroll
            for (int f = 0; f < 4; ++f)
                b[f] = *(const bf16x8*)(wsm + (sec * 64 + f * 16 + c) * WSR + ko);
#pragma unroll
            for (int m = 0; m < 2; ++m)
#pragma unroll
                for (int f = 0; f < 4; ++f)
                    acc[m][f] = __builtin_amdgcn_mfma_f32_16x16x32_bf16(a[m], b[f], acc[m][f], 0, 0, 0);
        }
    }
    __syncthreads();   // all LDS reads done before kT/vT overlay writes

    // ---- epilogue: C/D frag mapping col = c + 16f, row = 32r + 16m + 4g + reg
    if (sec == 0) {
#pragma unroll
        for (int m = 0; m < 2; ++m)
#pragma unroll
            for (int f = 0; f < 4; ++f)
#pragma unroll
                for (int reg = 0; reg < 4; ++reg) {
                    const long row = rowBase + r * 32 + m * 16 + g * 4 + reg;
                    qphi[row * DK + f * 16 + c] = f2bf(phi_f(acc[m][f][reg]));
                }
    } else if (sec == 1) {
        float s[4] = {0.f, 0.f, 0.f, 0.f};
#pragma unroll
        for (int m = 0; m < 2; ++m)
#pragma unroll
            for (int f = 0; f < 4; ++f) {
                float p0 = phi_f(acc[m][f][0]), p1 = phi_f(acc[m][f][1]);
                float p2 = phi_f(acc[m][f][2]), p3 = phi_f(acc[m][f][3]);
                s[f] += p0 + p1 + p2 + p3;
                const int col = f * 16 + c;
                const int row0 = r * 32 + m * 16 + g * 4;
                *(unsigned*)(kT + col * TS + row0)     = (unsigned)f2bf(p0) | ((unsigned)f2bf(p1) << 16);
                *(unsigned*)(kT + col * TS + row0 + 2) = (unsigned)f2bf(p2) | ((unsigned)f2bf(p3) << 16);
            }
#pragma unroll
        for (int f = 0; f < 4; ++f) {
            s[f] += __shfl_xor(s[f], 16);
            s[f] += __shfl_xor(s[f], 32);
        }
        if (l < 16)
#pragma unroll
            for (int f = 0; f < 4; ++f) atomicAdd(&ksum_lds[f * 16 + c], s[f]);
    } else {
#pragma unroll
        for (int m = 0; m < 2; ++m)
#pragma unroll
            for (int f = 0; f < 4; ++f) {
                const int col = f * 16 + c;
                const int row0 = r * 32 + m * 16 + g * 4;
                *(unsigned*)(vT + col * TS + row0) =
                    (unsigned)f2bf(acc[m][f][0]) | ((unsigned)f2bf(acc[m][f][1]) << 16);
                *(unsigned*)(vT + col * TS + row0 + 2) =
                    (unsigned)f2bf(acc[m][f][2]) | ((unsigned)f2bf(acc[m][f][3]) << 16);
            }
    }
    __syncthreads();

    // ---- per-block KV partial: KV[64][64] = KphiT(64x128) @ V(128x64)
    float* partBlk = part + (long)blockIdx.x * 4160;
    if (w < 4) {
        f32x4 kv[4];
#pragma unroll
        for (int f = 0; f < 4; ++f) kv[f] = (f32x4){0.f, 0.f, 0.f, 0.f};
#pragma unroll
        for (int ks = 0; ks < 4; ++ks) {
            const int ko = ks * 32 + g * 8;
            bf16x8 a = *(const bf16x8*)(kT + (w * 16 + c) * TS + ko);
#pragma unroll
            for (int f = 0; f < 4; ++f) {
                bf16x8 b = *(const bf16x8*)(vT + (f * 16 + c) * TS + ko);
                kv[f] = __builtin_amdgcn_mfma_f32_16x16x32_bf16(a, b, kv[f], 0, 0, 0);
            }
        }
#pragma unroll
        for (int f = 0; f < 4; ++f)
#pragma unroll
            for (int reg = 0; reg < 4; ++reg)
                partBlk[(w * 16 + g * 4 + reg) * 64 + f * 16 + c] = kv[f][reg];
    }
    if (tid < 64) partBlk[4096 + tid] = ksum_lds[tid];
}

// -------------------------------------------------------------- reduce ----
// v2: 65 blocks x 512 threads, no atomics. Block b owns e in [b*64, b*64+64).
// 8 b-groups of 64 lanes each sum 128 partials (unroll-16 -> 16 outstanding
// loads/lane, ~520 waves chip-wide -> BW-bound ~3-5 us), LDS combine, store.
__global__ __launch_bounds__(512) void la_reduce(const float* __restrict__ part,
                                                 float* __restrict__ finals) {
    __shared__ float red[8][64];
    const int tid = threadIdx.x;
    const int el  = tid & 63;
    const int bg  = tid >> 6;                    // 0..7
    const int e   = blockIdx.x * 64 + el;        // 65*64 = 4160 exactly
    const float* p = part + (long)bg * 128 * 4160 + e;
    float s = 0.f;
#pragma unroll 16
    for (int b = 0; b < 128; ++b) s += p[(long)b * 4160];
    red[bg][el] = s;
    __syncthreads();
    if (bg == 0) {
        float t = s;
#pragma unroll
        for (int q = 1; q < 8; ++q) t += red[q][el];
        finals[e] = t;
    }
}

// ----------------------------------------------------------------- out ----
__global__ __launch_bounds__(256) void la_out(
    const unsigned short* __restrict__ qphi, const float* __restrict__ finals,
    float* __restrict__ out)
{
    __shared__ __align__(16) unsigned short kvT[64 * 72];  // KV^T bf16, stride 72
    __shared__ float ks_l[64];
    __shared__ float z_l[4][32];

    const int tid = threadIdx.x;
    const int w = tid >> 6, l = tid & 63, c = l & 15, g = l >> 4;

    const int e0 = tid << 4;
    const int kk = e0 >> 6, j0 = e0 & 63;
#pragma unroll
    for (int q = 0; q < 16; ++q) kvT[(j0 + q) * 72 + kk] = f2bf(finals[e0 + q]);
    if (tid < 64) ks_l[tid] = finals[4096 + tid];
    __syncthreads();

    const long rowBase = (long)blockIdx.x * 128 + w * 32;

    bf16x8 a[2][2];
#pragma unroll
    for (int m = 0; m < 2; ++m)
#pragma unroll
        for (int ks = 0; ks < 2; ++ks)
            a[m][ks] = *(const bf16x8*)(qphi + (rowBase + m * 16 + c) * DK + ks * 32 + g * 8);

#pragma unroll
    for (int m = 0; m < 2; ++m) {
        float den = 0.f;
#pragma unroll
        for (int ks = 0; ks < 2; ++ks)
#pragma unroll
            for (int i = 0; i < 8; ++i)
                den += bf2f((unsigned short)a[m][ks][i]) * ks_l[ks * 32 + g * 8 + i];
        den += __shfl_xor(den, 16);
        den += __shfl_xor(den, 32);
        if (l < 16) z_l[w][m * 16 + c] = 1.f / (den + 1e-8f);
    }

    f32x4 acc[2][4];
#pragma unroll
    for (int m = 0; m < 2; ++m)
#pragma unroll
        for (int f = 0; f < 4; ++f) acc[m][f] = (f32x4){0.f, 0.f, 0.f, 0.f};
#pragma unroll
    for (int ks = 0; ks < 2; ++ks)
#pragma unroll
        for (int f = 0; f < 4; ++f) {
            bf16x8 b = *(const bf16x8*)(kvT + (f * 16 + c) * 72 + ks * 32 + g * 8);
#pragma unroll
            for (int m = 0; m < 2; ++m)
                acc[m][f] = __builtin_amdgcn_mfma_f32_16x16x32_bf16(a[m][ks], b, acc[m][f], 0, 0, 0);
        }

#pragma unroll
    for (int m = 0; m < 2; ++m)
#pragma unroll
        for (int reg = 0; reg < 4; ++reg) {
            const int row16 = g * 4 + reg;
            const float z = z_l[w][m * 16 + row16];
#pragma unroll
            for (int f = 0; f < 4; ++f)
                out[(rowBase + m * 16 + row16) * DK + f * 16 + c] = acc[m][f][reg] * z;
        }
}

// -------------------------------------------------------------- launch ----
extern "C" void kernel_launch(void* const* d_in, const int* in_sizes, int n_in,
                              void* d_out, int out_size, void* d_ws, size_t ws_size,
                              hipStream_t stream) {
    const float* X  = (const float*)d_in[0];
    const float* Wq = (const float*)d_in[1];
    const float* Wk = (const float*)d_in[2];
    const float* Wv = (const float*)d_in[3];
    float* out = (float*)d_out;

    char* ws = (char*)d_ws;
    unsigned short* qphi  = (unsigned short*)ws;
    unsigned short* wbfT  = (unsigned short*)(ws + 16777216);
    float*          part  = (float*)(ws + 16777216 + 196608);
    float*          fin   = (float*)(ws + 16777216 + 196608 + 17039360);

    la_prep  <<<96,   1024, 0, stream>>>(Wq, Wk, Wv, wbfT);
    la_main  <<<1024,  768, 0, stream>>>(X, wbfT, qphi, part);
    la_reduce<<<65,    512, 0, stream>>>(part, fin);
    la_out   <<<1024,  256, 0, stream>>>(qphi, fin, out);
}